// Round 9
// baseline (579.839 us; speedup 1.0000x reference)
//
#include <hip/hip_runtime.h>
#include <hip/hip_bf16.h>

#define B_   16
#define LQ   2048
#define LK   2048
#define HD   64
#define QT   32
#define KT   64
#define NKT  (LK / KT)         // 32
#define NWG  (B_ * (LQ / QT))  // 1024
#define NXCD 8
#define EC   0.1803368801f     // 0.125 * log2(e)

typedef __attribute__((ext_vector_type(8))) short bf16x8;
typedef __attribute__((ext_vector_type(4))) float f32x4;

#define MFMA __builtin_amdgcn_mfma_f32_16x16x32_bf16

// chunk-XOR-swizzled word index into a [32][64] fp32 LDS tile.
// 4-float chunks permuted by row&15 -> b128 reads/writes stay aligned,
// column accesses spread across banks.
__device__ __forceinline__ int idx32(int row, int col) {
    return row * 64 + ((((col >> 2) ^ (row & 15)) << 2) | (col & 3));
}

__device__ __forceinline__ bf16x8 cvt8(float4 a, float4 b) {
    union { bf16x8 v; __hip_bfloat162 h[4]; } u;
    u.h[0] = __float22bfloat162_rn(make_float2(a.x, a.y));
    u.h[1] = __float22bfloat162_rn(make_float2(a.z, a.w));
    u.h[2] = __float22bfloat162_rn(make_float2(b.x, b.y));
    u.h[3] = __float22bfloat162_rn(make_float2(b.z, b.w));
    return u.v;
}
__device__ __forceinline__ bf16x8 cvt8s(const float* v) {
    union { bf16x8 r; __hip_bfloat162 h[4]; } u;
    #pragma unroll
    for (int i = 0; i < 4; ++i)
        u.h[i] = __float22bfloat162_rn(make_float2(v[2 * i], v[2 * i + 1]));
    return u.r;
}

__global__ __launch_bounds__(384, 6) void sdpa_kernel(
    const float* __restrict__ qg, const float* __restrict__ kg,
    const float* __restrict__ vg, float* __restrict__ ctx,
    float* __restrict__ att)
{
    __shared__ float P32[2][QT * 64];   // fp32 P tile, double-buffered (16 KB)
    __shared__ float redl[4][QT];
    __shared__ float invl[QT];

    const int tid  = threadIdx.x;
    const int wave = tid >> 6;          // 0..3 compute, 4..5 store
    const int lane = tid & 63;
    const int g    = lane >> 4;
    const int c    = lane & 15;

    // XCD-aware bijective swizzle (keeps K/V in the per-XCD L2)
    const int bid = (int)blockIdx.x;
    const int lid = (bid % NXCD) * (NWG / NXCD) + bid / NXCD;
    const int b  = lid / (LQ / QT);
    const int qt = lid % (LQ / QT);

    const float* qp = qg + (size_t)(b * LQ + qt * QT) * HD;
    const float* kp = kg + (size_t)b * LK * HD;
    const float* vp = vg + (size_t)b * LK * HD;
    float* ctxp = ctx + (size_t)(b * LQ + qt * QT) * HD;
    float* attp = att + (size_t)(b * LQ + qt * QT) * LK;

    // masked wave index so store waves never form wild pointers
    const int cw4 = wave & 3;
    const float* kl = kp + (cw4 * 16 + c) * HD + g * 8;
    const float* vl = vp + (g * 8) * HD + cw4 * 16 + c;

    bf16x8 aQ[2][2];
    float il[2][4];

    if (wave < 4) {
        // ---- Q fragments straight from global ----
        #pragma unroll
        for (int m = 0; m < 2; ++m)
            #pragma unroll
            for (int h = 0; h < 2; ++h) {
                const float* p = qp + (m * 16 + c) * HD + h * 32 + g * 8;
                aQ[m][h] = cvt8(*reinterpret_cast<const float4*>(p),
                                *reinterpret_cast<const float4*>(p + 4));
            }

        // ---- pass 1: rowsums of exp (1-deep prefetch, loads only) ----
        float lsum[2][4] = {{0.f,0.f,0.f,0.f},{0.f,0.f,0.f,0.f}};
        float4 ka0 = *reinterpret_cast<const float4*>(kl);
        float4 ka1 = *reinterpret_cast<const float4*>(kl + 4);
        float4 kb0 = *reinterpret_cast<const float4*>(kl + 32);
        float4 kb1 = *reinterpret_cast<const float4*>(kl + 36);
        #pragma unroll 1
        for (int t = 0; t < NKT; ++t) {
            bf16x8 bK0 = cvt8(ka0, ka1);
            bf16x8 bK1 = cvt8(kb0, kb1);
            if (t + 1 < NKT) {
                const float* n = kl + (size_t)(t + 1) * KT * HD;
                ka0 = *reinterpret_cast<const float4*>(n);
                ka1 = *reinterpret_cast<const float4*>(n + 4);
                kb0 = *reinterpret_cast<const float4*>(n + 32);
                kb1 = *reinterpret_cast<const float4*>(n + 36);
            }
            #pragma unroll
            for (int m = 0; m < 2; ++m) {
                f32x4 acc = {0.f, 0.f, 0.f, 0.f};
                acc = MFMA(aQ[m][0], bK0, acc, 0, 0, 0);
                acc = MFMA(aQ[m][1], bK1, acc, 0, 0, 0);
                #pragma unroll
                for (int r = 0; r < 4; ++r)
                    lsum[m][r] += exp2f(acc[r] * EC);
            }
        }
        // lane-group reduce
        #pragma unroll
        for (int m = 0; m < 2; ++m)
            #pragma unroll
            for (int r = 0; r < 4; ++r) {
                float s = lsum[m][r];
                s += __shfl_xor(s, 1, 64);
                s += __shfl_xor(s, 2, 64);
                s += __shfl_xor(s, 4, 64);
                s += __shfl_xor(s, 8, 64);
                lsum[m][r] = s;
            }
        if (c == 0) {
            #pragma unroll
            for (int m = 0; m < 2; ++m)
                #pragma unroll
                for (int r = 0; r < 4; ++r)
                    redl[wave][m * 16 + g * 4 + r] = lsum[m][r];
        }
    }
    __syncthreads();
    if (tid < QT) {
        float s = redl[0][tid] + redl[1][tid] + redl[2][tid] + redl[3][tid];
        invl[tid] = 1.0f / s;
    }
    __syncthreads();
    if (wave < 4) {
        #pragma unroll
        for (int m = 0; m < 2; ++m)
            #pragma unroll
            for (int r = 0; r < 4; ++r)
                il[m][r] = invl[m * 16 + g * 4 + r];
    }

    // ---- pass 2: compute waves produce P32; store waves stream att ----
    f32x4 cacc[2];
    cacc[0] = (f32x4){0.f, 0.f, 0.f, 0.f};
    cacc[1] = (f32x4){0.f, 0.f, 0.f, 0.f};

    float4 ka0, ka1, kb0, kb1;
    float va[8], vb[8];
    if (wave < 4) {
        ka0 = *reinterpret_cast<const float4*>(kl);
        ka1 = *reinterpret_cast<const float4*>(kl + 4);
        kb0 = *reinterpret_cast<const float4*>(kl + 32);
        kb1 = *reinterpret_cast<const float4*>(kl + 36);
        #pragma unroll
        for (int j = 0; j < 8; ++j) {
            va[j] = vl[(size_t)j * HD];
            vb[j] = vl[(size_t)(32 + j) * HD];
        }
    }

    int buf = 0;
    #pragma unroll 1
    for (int t = 0; t < NKT; ++t) {
        bf16x8 bV0, bV1;
        if (wave < 4) {
            bf16x8 bK0 = cvt8(ka0, ka1);
            bf16x8 bK1 = cvt8(kb0, kb1);
            bV0 = cvt8s(va);
            bV1 = cvt8s(vb);

            float pr[2][4];
            #pragma unroll
            for (int m = 0; m < 2; ++m) {
                f32x4 acc = {0.f, 0.f, 0.f, 0.f};
                acc = MFMA(aQ[m][0], bK0, acc, 0, 0, 0);
                acc = MFMA(aQ[m][1], bK1, acc, 0, 0, 0);
                #pragma unroll
                for (int r = 0; r < 4; ++r)
                    pr[m][r] = exp2f(acc[r] * EC) * il[m][r];
            }

            // prefetch next K/V (ONLY loads ever enter this wave's vmcnt)
            if (t + 1 < NKT) {
                const float* n = kl + (size_t)(t + 1) * KT * HD;
                ka0 = *reinterpret_cast<const float4*>(n);
                ka1 = *reinterpret_cast<const float4*>(n + 4);
                kb0 = *reinterpret_cast<const float4*>(n + 32);
                kb1 = *reinterpret_cast<const float4*>(n + 36);
                const float* nv = vl + (size_t)(t + 1) * KT * HD;
                #pragma unroll
                for (int j = 0; j < 8; ++j) {
                    va[j] = nv[(size_t)j * HD];
                    vb[j] = nv[(size_t)(32 + j) * HD];
                }
            }

            // publish fp32 P tile
            #pragma unroll
            for (int m = 0; m < 2; ++m)
                #pragma unroll
                for (int r = 0; r < 4; ++r)
                    P32[buf][idx32(m * 16 + g * 4 + r, wave * 16 + c)] = pr[m][r];
        }

        // LDS-only barrier: no vmcnt drain in any wave
        asm volatile("s_waitcnt lgkmcnt(0)\n\ts_barrier" ::: "memory");

        if (wave < 4) {
            // PV from fp32 P (read + convert)
            #pragma unroll
            for (int m = 0; m < 2; ++m) {
                const int row = m * 16 + c;
                float4 p0 = *reinterpret_cast<const float4*>(&P32[buf][idx32(row, g * 8)]);
                float4 p1 = *reinterpret_cast<const float4*>(&P32[buf][idx32(row, g * 8 + 4)]);
                float4 p2 = *reinterpret_cast<const float4*>(&P32[buf][idx32(row, 32 + g * 8)]);
                float4 p3 = *reinterpret_cast<const float4*>(&P32[buf][idx32(row, 36 + g * 8)]);
                bf16x8 aP0 = cvt8(p0, p1);
                bf16x8 aP1 = cvt8(p2, p3);
                cacc[m] = MFMA(aP0, bV0, cacc[m], 0, 0, 0);
                cacc[m] = MFMA(aP1, bV1, cacc[m], 0, 0, 0);
            }
        } else {
            // store waves: stream att. Each instr = 4 rows x 256B contiguous
            // (16-lane groups) = 8 fully-covered 128B lines.
            const int sw  = wave - 4;
            const int cwd = c * 4;                    // col dword 0..60
            #pragma unroll
            for (int i = 0; i < 4; ++i) {
                const int row = sw * 16 + i * 4 + g;
                float4 vdat = *reinterpret_cast<const float4*>(
                    &P32[buf][idx32(row, cwd)]);
                *reinterpret_cast<float4*>(
                    attp + (size_t)row * LK + t * KT + cwd) = vdat;
            }
        }
        buf ^= 1;
    }

    if (wave < 4) {
        #pragma unroll
        for (int m = 0; m < 2; ++m)
            #pragma unroll
            for (int r = 0; r < 4; ++r)
                ctxp[(m * 16 + g * 4 + r) * HD + wave * 16 + c] = cacc[m][r];
    }
}

extern "C" void kernel_launch(void* const* d_in, const int* in_sizes, int n_in,
                              void* d_out, int out_size, void* d_ws, size_t ws_size,
                              hipStream_t stream) {
    const float* q = (const float*)d_in[0];
    const float* k = (const float*)d_in[1];
    const float* v = (const float*)d_in[2];
    float* ctx = (float*)d_out;                  // [16,2048,64]
    float* att = ctx + (size_t)B_ * LQ * HD;     // [16,2048,2048]
    dim3 grid(NWG);
    sdpa_kernel<<<grid, dim3(384), 0, stream>>>(q, k, v, ctx, att);
}